// Round 17
// baseline (554.683 us; speedup 1.0000x reference)
//
#include <hip/hip_runtime.h>
#include <hip/hip_bf16.h>

#define B_ 2
#define T_ 1024
#define D_ 1024
#define H_ 16
#define DH_ 64
#define F_ 2048
#define E_ 8
#define M_ 2048   // B*T tokens

typedef _Float16 half8 __attribute__((ext_vector_type(8)));
typedef _Float16 half4v __attribute__((ext_vector_type(4)));
typedef float f32x4 __attribute__((ext_vector_type(4)));

// ===== numpy-style pairwise sum of a[0..K), K in {1024, 2048}, one wave =====
template<bool ABS>
__device__ __forceinline__ float np_pairwise_wave(const float* a, int K, int lane) {
  int nb = K >> 7;
  float s = 0.f;
  if (lane < nb) {
    const float* p = a + (lane << 7);
    float r[8];
    #pragma unroll
    for (int j = 0; j < 8; ++j) r[j] = ABS ? fabsf(p[j]) : p[j];
    for (int i = 8; i < 128; i += 8)
      #pragma unroll
      for (int j = 0; j < 8; ++j) r[j] += ABS ? fabsf(p[i + j]) : p[i + j];
    s = ((r[0] + r[1]) + (r[2] + r[3])) + ((r[4] + r[5]) + (r[6] + r[7]));
  }
  for (int off = 1; off < nb; off <<= 1) s += __shfl_xor(s, off);
  return __shfl(s, 0);
}

// ===== ALL weight scales + prequant + lambda in ONE launch =====
__global__ __launch_bounds__(64) void k_scaleq_all(
    const float* __restrict__ Wq, const float* __restrict__ Wk,
    const float* __restrict__ Wv, const float* __restrict__ Wo,
    const float* __restrict__ sw1, const float* __restrict__ sw2,
    const float* __restrict__ ew1, const float* __restrict__ ew2,
    const float* __restrict__ lq, const float* __restrict__ lk,
    float* __restrict__ scWq, float* __restrict__ scWk,
    float* __restrict__ scWv, float* __restrict__ scWo,
    float* __restrict__ scS1, float* __restrict__ scS2,
    float* __restrict__ scE1, float* __restrict__ scE2,
    _Float16* __restrict__ QWq, _Float16* __restrict__ QWk,
    _Float16* __restrict__ QWv, _Float16* __restrict__ QWo,
    _Float16* __restrict__ QS1, _Float16* __restrict__ QS2,
    _Float16* __restrict__ QE1, _Float16* __restrict__ QE2,
    float* __restrict__ lam)
{
  int r = blockIdx.x, lane = threadIdx.x;
  if (r == 33792) {   // lambda block
    float mq = np_pairwise_wave<false>(lq, 1024, lane) / 1024.0f;
    float mk = np_pairwise_wave<false>(lk, 1024, lane) / 1024.0f;
    if (lane == 0) {
      float l = expf(mq - mk);
      lam[0] = fminf(2.0f, fmaxf(0.1f, l));
    }
    return;
  }
  const float* W; float* sc; _Float16* qo; int K; int rr;
  if      (r < 2048)  { W = Wq;  sc = scWq; qo = QWq; K = 1024; rr = r; }
  else if (r < 4096)  { W = Wk;  sc = scWk; qo = QWk; K = 1024; rr = r - 2048; }
  else if (r < 5120)  { W = Wv;  sc = scWv; qo = QWv; K = 1024; rr = r - 4096; }
  else if (r < 6144)  { W = Wo;  sc = scWo; qo = QWo; K = 1024; rr = r - 5120; }
  else if (r < 8192)  { W = sw1; sc = scS1; qo = QS1; K = 1024; rr = r - 6144; }
  else if (r < 9216)  { W = sw2; sc = scS2; qo = QS2; K = 2048; rr = r - 8192; }
  else if (r < 25600) { W = ew1; sc = scE1; qo = QE1; K = 1024; rr = r - 9216; }
  else                { W = ew2; sc = scE2; qo = QE2; K = 2048; rr = r - 25600; }
  const float* row = W + (size_t)rr * K;
  float S = np_pairwise_wave<true>(row, K, lane);
  float s = fmaxf(S / (float)K, 1e-5f);
  if (lane == 0) sc[rr] = s;
  _Float16* dst = qo + (size_t)rr * K;
  for (int k = lane * 4; k < K; k += 256) {
    float4 w = *reinterpret_cast<const float4*>(row + k);
    float wv[4] = {w.x, w.y, w.z, w.w};
    half4v q4;
    #pragma unroll
    for (int j = 0; j < 4; ++j) {
      float q = rintf(wv[j] / s);
      q = fminf(1.f, fmaxf(-1.f, q));
      q4[j] = (_Float16)q;
    }
    *reinterpret_cast<half4v*>(dst + k) = q4;
  }
}

// ===== layernorm f32 -> fp16 hi/lo split (for x -> H1) =====
__global__ __launch_bounds__(256) void k_layernorm_split(const float* __restrict__ in,
                                                         const float* __restrict__ g,
                                                         const float* __restrict__ b,
                                                         _Float16* __restrict__ oh,
                                                         _Float16* __restrict__ ol, int Dd) {
  #pragma clang fp contract(off)
  __shared__ float row[2048];
  __shared__ float sq[2048];
  __shared__ float stat[2];
  int m = blockIdx.x, tid = threadIdx.x;
  const float* src = in + (size_t)m * Dd;
  for (int d = tid; d < Dd; d += 256) row[d] = src[d];
  __syncthreads();
  if (tid < 64) {
    float S = np_pairwise_wave<false>(row, Dd, tid);
    if (tid == 0) stat[0] = S;
  }
  __syncthreads();
  float mean = stat[0] / (float)Dd;
  for (int d = tid; d < Dd; d += 256) { float t = row[d] - mean; sq[d] = t * t; }
  __syncthreads();
  if (tid < 64) {
    float S = np_pairwise_wave<false>(sq, Dd, tid);
    if (tid == 0) stat[1] = S;
  }
  __syncthreads();
  float var = stat[1] / (float)Dd;
  float rs = 1.0f / sqrtf(var + 1e-5f);
  #pragma unroll 1
  for (int d = tid; d < Dd; d += 256) {
    float t = row[d] - mean;
    float u = t * rs;
    float v = u * g[d];
    float w = v + b[d];
    _Float16 hv = (_Float16)w;
    oh[(size_t)m * Dd + d] = hv;
    ol[(size_t)m * Dd + d] = (_Float16)((w - (float)hv) * 2048.0f);
  }
}

// ===== fused Q-LN (f32 in-place) + K-LN (split) in one launch =====
__global__ __launch_bounds__(256) void k_lnqk(float* __restrict__ QP,
                                              const float* __restrict__ qg, const float* __restrict__ qb,
                                              const float* __restrict__ KP,
                                              const float* __restrict__ kg, const float* __restrict__ kb,
                                              _Float16* __restrict__ khg, _Float16* __restrict__ klg) {
  #pragma clang fp contract(off)
  __shared__ float row[2048];
  __shared__ float sq[2048];
  __shared__ float stat[2];
  int blk = blockIdx.x, tid = threadIdx.x;
  bool isQ = blk < 2048;
  int m = isQ ? blk : (blk - 2048);
  const float* src = (isQ ? (const float*)QP : KP) + (size_t)m * 2048;
  for (int d = tid; d < 2048; d += 256) row[d] = src[d];
  __syncthreads();
  if (tid < 64) {
    float S = np_pairwise_wave<false>(row, 2048, tid);
    if (tid == 0) stat[0] = S;
  }
  __syncthreads();
  float mean = stat[0] / 2048.0f;
  for (int d = tid; d < 2048; d += 256) { float t = row[d] - mean; sq[d] = t * t; }
  __syncthreads();
  if (tid < 64) {
    float S = np_pairwise_wave<false>(sq, 2048, tid);
    if (tid == 0) stat[1] = S;
  }
  __syncthreads();
  float var = stat[1] / 2048.0f;
  float rs = 1.0f / sqrtf(var + 1e-5f);
  if (isQ) {
    float* dst = QP + (size_t)m * 2048;
    for (int d = tid; d < 2048; d += 256) {
      float t = row[d] - mean;
      float u = t * rs;
      float v = u * qg[d];
      dst[d] = v + qb[d];
    }
  } else {
    #pragma unroll 1
    for (int d = tid; d < 2048; d += 256) {
      float t = row[d] - mean;
      float u = t * rs;
      float v = u * kg[d];
      float w = v + kb[d];
      _Float16 hv = (_Float16)w;
      khg[(size_t)m * 2048 + d] = hv;
      klg[(size_t)m * 2048 + d] = (_Float16)((w - (float)hv) * 2048.0f);
    }
  }
}

// ===== fused double layernorm =====
__global__ __launch_bounds__(256) void k_lnln(const float* __restrict__ in,
                                              const float* __restrict__ g1, const float* __restrict__ b1,
                                              const float* __restrict__ g2, const float* __restrict__ b2,
                                              float* __restrict__ outf,
                                              _Float16* __restrict__ outh) {
  #pragma clang fp contract(off)
  __shared__ float row[1024];
  __shared__ float tmp[1024];
  __shared__ float stat[2];
  int m = blockIdx.x, tid = threadIdx.x;
  const float* src = in + (size_t)m * 1024;
  for (int d = tid; d < 1024; d += 256) row[d] = src[d];
  __syncthreads();
  if (tid < 64) { float S = np_pairwise_wave<false>(row, 1024, tid); if (tid == 0) stat[0] = S; }
  __syncthreads();
  float mean = stat[0] / 1024.0f;
  for (int d = tid; d < 1024; d += 256) { float t = row[d] - mean; tmp[d] = t * t; }
  __syncthreads();
  if (tid < 64) { float S = np_pairwise_wave<false>(tmp, 1024, tid); if (tid == 0) stat[1] = S; }
  __syncthreads();
  float rs = 1.0f / sqrtf(stat[1] / 1024.0f + 1e-5f);
  for (int d = tid; d < 1024; d += 256) {
    float t = row[d] - mean;
    float u = t * rs;
    float v = u * g1[d];
    tmp[d] = v + b1[d];
  }
  __syncthreads();
  if (tid < 64) { float S = np_pairwise_wave<false>(tmp, 1024, tid); if (tid == 0) stat[0] = S; }
  __syncthreads();
  float mean2 = stat[0] / 1024.0f;
  for (int d = tid; d < 1024; d += 256) { float t = tmp[d] - mean2; row[d] = t * t; }
  __syncthreads();
  if (tid < 64) { float S = np_pairwise_wave<false>(row, 1024, tid); if (tid == 0) stat[1] = S; }
  __syncthreads();
  float rs2 = 1.0f / sqrtf(stat[1] / 1024.0f + 1e-5f);
  for (int d = tid; d < 1024; d += 256) {
    float t = tmp[d] - mean2;
    float u = t * rs2;
    float v = u * g2[d];
    float w = v + b2[d];
    outf[(size_t)m * 1024 + d] = w;
    outh[(size_t)m * 1024 + d] = (_Float16)w;
  }
}

// ===== generic MFMA GEMM (used for Wo only) =====
template<int EPI, int XM, int DUAL>
__global__ __launch_bounds__(256) void k_mgemm(
    const _Float16* __restrict__ Agh, const _Float16* __restrict__ Agl, int lda,
    const _Float16* __restrict__ Wh, const float* __restrict__ scf,
    float* __restrict__ Cout, _Float16* __restrict__ Ch, _Float16* __restrict__ Ch2,
    int ldc, int N, int K,
    const float* __restrict__ res, const float* __restrict__ add2,
    const int* __restrict__ offs, const int* __restrict__ tlist,
    const float* __restrict__ topp)
{
  int e = XM ? blockIdx.z : 0;
  int mbase = 0, mcount = M_;
  const float* sc = scf;
  const _Float16* Whb = Wh;
  if (XM) {
    mbase = offs[e]; mcount = offs[e + 1] - mbase;
    Whb = Wh + (size_t)e * N * K;
    sc = scf + (size_t)e * N;
  }
  int m0 = blockIdx.y * 128;
  if (XM && m0 >= mcount) return;
  int n0 = blockIdx.x * 64;

  __shared__ __align__(16) _Float16 As[4][128][8];
  __shared__ __align__(16) _Float16 Als[DUAL ? 4 : 1][128][8];
  __shared__ __align__(16) _Float16 Qs[4][64][8];

  int tid = threadIdx.x;
  int lm  = tid >> 1;
  int kcA = (tid & 1) * 16;
  int lw  = tid >> 2;
  int kcW = (tid & 3) * 8;

  int am  = m0 + lm;
  int amc = XM ? ((am < mcount) ? am : (mcount - 1)) : am;
  int arow;
  if (XM == 1)      arow = tlist[mbase + amc];
  else if (XM == 2) arow = mbase + amc;
  else              arow = am;
  const _Float16* Arh = Agh + (size_t)arow * lda;
  const _Float16* Arl = DUAL ? (Agl + (size_t)arow * lda) : nullptr;
  const _Float16* Wrh = Whb + (size_t)(n0 + lw) * K;

  int wv = tid >> 6, lane = tid & 63;
  int wm = wv >> 1, wn = wv & 1;
  int ks = lane >> 4, fr = lane & 15;

  f32x4 acch[4][2], accl[4][2];
  #pragma unroll
  for (int i = 0; i < 4; i++)
    #pragma unroll
    for (int j = 0; j < 2; j++) { acch[i][j] = (f32x4)0.f; accl[i][j] = (f32x4)0.f; }

  for (int kt = 0; kt < K; kt += 32) {
    half8 a0 = *reinterpret_cast<const half8*>(Arh + kt + kcA);
    half8 a1 = *reinterpret_cast<const half8*>(Arh + kt + kcA + 8);
    half8 b0, b1;
    if (DUAL) {
      b0 = *reinterpret_cast<const half8*>(Arl + kt + kcA);
      b1 = *reinterpret_cast<const half8*>(Arl + kt + kcA + 8);
    }
    half8 qv = *reinterpret_cast<const half8*>(Wrh + kt + kcW);
    __syncthreads();
    int sA = kcA >> 3;
    *reinterpret_cast<half8*>(&As[sA][lm][0])     = a0;
    *reinterpret_cast<half8*>(&As[sA + 1][lm][0]) = a1;
    if (DUAL) {
      *reinterpret_cast<half8*>(&Als[sA][lm][0])     = b0;
      *reinterpret_cast<half8*>(&Als[sA + 1][lm][0]) = b1;
    }
    *reinterpret_cast<half8*>(&Qs[kcW >> 3][lw][0]) = qv;
    __syncthreads();
    half8 bfr0 = *reinterpret_cast<half8*>(&Qs[ks][wn * 32 + fr][0]);
    half8 bfr1 = *reinterpret_cast<half8*>(&Qs[ks][wn * 32 + 16 + fr][0]);
    #pragma unroll
    for (int i = 0; i < 4; i++) {
      half8 ah = *reinterpret_cast<half8*>(&As[ks][wm * 64 + i * 16 + fr][0]);
      acch[i][0] = __builtin_amdgcn_mfma_f32_16x16x32_f16(ah, bfr0, acch[i][0], 0, 0, 0);
      acch[i][1] = __builtin_amdgcn_mfma_f32_16x16x32_f16(ah, bfr1, acch[i][1], 0, 0, 0);
      if (DUAL) {
        half8 al = *reinterpret_cast<half8*>(&Als[ks][wm * 64 + i * 16 + fr][0]);
        accl[i][0] = __builtin_amdgcn_mfma_f32_16x16x32_f16(al, bfr0, accl[i][0], 0, 0, 0);
        accl[i][1] = __builtin_amdgcn_mfma_f32_16x16x32_f16(al, bfr1, accl[i][1], 0, 0, 0);
      }
    }
  }

  #pragma unroll
  for (int j = 0; j < 2; j++) {
    int col = n0 + wn * 32 + j * 16 + fr;
    float scl = sc[col];
    #pragma unroll
    for (int i = 0; i < 4; i++) {
      #pragma unroll
      for (int r = 0; r < 4; r++) {
        int lrow = m0 + wm * 64 + i * 16 + ks * 4 + r;
        if (XM && lrow >= mcount) continue;
        int orow;
        if (XM == 1)      orow = mbase + lrow;
        else if (XM == 2) orow = tlist[mbase + lrow];
        else              orow = lrow;
        float v = acch[i][j][r];
        if (DUAL) v += accl[i][j][r] * (1.0f / 2048.0f);
        v *= scl;
        if (EPI == 1) {
          v = v * (1.0f / (1.0f + __expf(-v)));
          Ch[(size_t)orow * ldc + col] = (_Float16)v;
        } else if (EPI == 2) {
          Cout[(size_t)orow * ldc + col] = res[(size_t)orow * ldc + col] + v;
        } else {
          Cout[(size_t)orow * ldc + col] = v;
        }
      }
    }
  }
}

// ===== fused Q+K+V GEMM (DUAL, one launch, 80 n-tiles) =====
__global__ __launch_bounds__(256) void k_mgemm_qkv(
    const _Float16* __restrict__ Agh, const _Float16* __restrict__ Agl,
    const _Float16* __restrict__ WQ_, const _Float16* __restrict__ WK_, const _Float16* __restrict__ WV_,
    const float* __restrict__ scq, const float* __restrict__ sck, const float* __restrict__ scv,
    float* __restrict__ Cq, float* __restrict__ Ck,
    _Float16* __restrict__ Vth, _Float16* __restrict__ Vtl)
{
  int nt = blockIdx.x;
  int sel = (nt < 32) ? 0 : (nt < 64 ? 1 : 2);
  int n0 = ((sel == 0) ? nt : (sel == 1) ? (nt - 32) : (nt - 64)) * 64;
  const _Float16* Wh = (sel == 0) ? WQ_ : (sel == 1) ? WK_ : WV_;
  const float* sc = (sel == 0) ? scq : (sel == 1) ? sck : scv;
  int m0 = blockIdx.y * 128;

  __shared__ __align__(16) _Float16 As[4][128][8];
  __shared__ __align__(16) _Float16 Als[4][128][8];
  __shared__ __align__(16) _Float16 Qs[4][64][8];

  int tid = threadIdx.x;
  int lm  = tid >> 1;
  int kcA = (tid & 1) * 16;
  int lw  = tid >> 2;
  int kcW = (tid & 3) * 8;

  const _Float16* Arh = Agh + (size_t)(m0 + lm) * 1024;
  const _Float16* Arl = Agl + (size_t)(m0 + lm) * 1024;
  const _Float16* Wrh = Wh + (size_t)(n0 + lw) * 1024;

  int wv = tid >> 6, lane = tid & 63;
  int wm = wv >> 1, wn = wv & 1;
  int ks = lane >> 4, fr = lane & 15;

  f32x4 acch[4][2], accl[4][2];
  #pragma unroll
  for (int i = 0; i < 4; i++)
    #pragma unroll
    for (int j = 0; j < 2; j++) { acch[i][j] = (f32x4)0.f; accl[i][j] = (f32x4)0.f; }

  for (int kt = 0; kt < 1024; kt += 32) {
    half8 a0 = *reinterpret_cast<const half8*>(Arh + kt + kcA);
    half8 a1 = *reinterpret_cast<const half8*>(Arh + kt + kcA + 8);
    half8 b0 = *reinterpret_cast<const half8*>(Arl + kt + kcA);
    half8 b1 = *reinterpret_cast<const half8*>(Arl + kt + kcA + 8);
    half8 qv = *reinterpret_cast<const half8*>(Wrh + kt + kcW);
    __syncthreads();
    int sA = kcA >> 3;
    *reinterpret_cast<half8*>(&As[sA][lm][0])      = a0;
    *reinterpret_cast<half8*>(&As[sA + 1][lm][0])  = a1;
    *reinterpret_cast<half8*>(&Als[sA][lm][0])     = b0;
    *reinterpret_cast<half8*>(&Als[sA + 1][lm][0]) = b1;
    *reinterpret_cast<half8*>(&Qs[kcW >> 3][lw][0]) = qv;
    __syncthreads();
    half8 bfr0 = *reinterpret_cast<half8*>(&Qs[ks][wn * 32 + fr][0]);
    half8 bfr1 = *reinterpret_cast<half8*>(&Qs[ks][wn * 32 + 16 + fr][0]);
    #pragma unroll
    for (int i = 0; i < 4; i++) {
      half8 ah = *reinterpret_cast<half8*>(&As[ks][wm * 64 + i * 16 + fr][0]);
      half8 al = *reinterpret_cast<half8*>(&Als[ks][wm * 64 + i * 16 + fr][0]);
      acch[i][0] = __builtin_amdgcn_mfma_f32_16x16x32_f16(ah, bfr0, acch[i][0], 0, 0, 0);
      acch[i][1] = __builtin_amdgcn_mfma_f32_16x16x32_f16(ah, bfr1, acch[i][1], 0, 0, 0);
      accl[i][0] = __builtin_amdgcn_mfma_f32_16x16x32_f16(al, bfr0, accl[i][0], 0, 0, 0);
      accl[i][1] = __builtin_amdgcn_mfma_f32_16x16x32_f16(al, bfr1, accl[i][1], 0, 0, 0);
    }
  }

  #pragma unroll
  for (int j = 0; j < 2; j++) {
    int col = n0 + wn * 32 + j * 16 + fr;
    float scl = sc[col];
    #pragma unroll
    for (int i = 0; i < 4; i++) {
      #pragma unroll
      for (int r = 0; r < 4; r++) {
        int orow = m0 + wm * 64 + i * 16 + ks * 4 + r;
        float v = (acch[i][j][r] + accl[i][j][r] * (1.0f / 2048.0f)) * scl;
        if (sel == 0) {
          Cq[(size_t)orow * 2048 + col] = v;
        } else if (sel == 1) {
          Ck[(size_t)orow * 2048 + col] = v;
        } else {
          int bb = orow >> 10, tok = orow & 1023;
          size_t vidx = ((size_t)(bb << 10) + col) * 1024 + tok;
          _Float16 hv = (_Float16)v;
          Vth[vidx] = hv;
          Vtl[vidx] = (_Float16)((v - (float)hv) * 2048.0f);
        }
      }
    }
  }
}

// ===== fused shared-w1 + expert-w1 GEMM (NLOOP=1, z=0 dense, z=1..8 expert) =====
__global__ __launch_bounds__(256) void k_mgemm_moe1(
    const _Float16* __restrict__ Agh,
    const _Float16* __restrict__ WhS, const _Float16* __restrict__ WhE,
    const float* __restrict__ scS, const float* __restrict__ scE,
    _Float16* __restrict__ CS, _Float16* __restrict__ CE,
    const int* __restrict__ offs, const int* __restrict__ tlist)
{
  int z = blockIdx.z;
  int mbase = 0, mcount = M_;
  const _Float16* Whb = WhS;
  const float* sc = scS;
  if (z > 0) {
    int e = z - 1;
    mbase = offs[e]; mcount = offs[e + 1] - mbase;
    Whb = WhE + (size_t)e * 2048 * 1024;
    sc = scE + (size_t)e * 2048;
  }
  int m0 = blockIdx.y * 128;
  if (z > 0 && m0 >= mcount) return;
  int n0 = blockIdx.x * 64;

  __shared__ __align__(16) _Float16 As[4][128][8];
  __shared__ __align__(16) _Float16 Qs[4][64][8];

  int tid = threadIdx.x;
  int lm  = tid >> 1;
  int kcA = (tid & 1) * 16;
  int lw  = tid >> 2;
  int kcW = (tid & 3) * 8;

  int am  = m0 + lm;
  int amc = (z > 0) ? ((am < mcount) ? am : (mcount - 1)) : am;
  int arow = (z > 0) ? tlist[mbase + amc] : am;
  const _Float16* Arh = Agh + (size_t)arow * 1024;
  const _Float16* Wrh = Whb + (size_t)(n0 + lw) * 1024;

  int wv = tid >> 6, lane = tid & 63;
  int wm = wv >> 1, wn = wv & 1;
  int ks = lane >> 4, fr = lane & 15;

  f32x4 acch[4][2];
  #pragma unroll
  for (int i = 0; i < 4; i++)
    #pragma unroll
    for (int j = 0; j < 2; j++) acch[i][j] = (f32x4)0.f;

  for (int kt = 0; kt < 1024; kt += 32) {
    half8 a0 = *reinterpret_cast<const half8*>(Arh + kt + kcA);
    half8 a1 = *reinterpret_cast<const half8*>(Arh + kt + kcA + 8);
    half8 qv = *reinterpret_cast<const half8*>(Wrh + kt + kcW);
    __syncthreads();
    int sA = kcA >> 3;
    *reinterpret_cast<half8*>(&As[sA][lm][0])     = a0;
    *reinterpret_cast<half8*>(&As[sA + 1][lm][0]) = a1;
    *reinterpret_cast<half8*>(&Qs[kcW >> 3][lw][0]) = qv;
    __syncthreads();
    half8 bfr0 = *reinterpret_cast<half8*>(&Qs[ks][wn * 32 + fr][0]);
    half8 bfr1 = *reinterpret_cast<half8*>(&Qs[ks][wn * 32 + 16 + fr][0]);
    #pragma unroll
    for (int i = 0; i < 4; i++) {
      half8 ah = *reinterpret_cast<half8*>(&As[ks][wm * 64 + i * 16 + fr][0]);
      acch[i][0] = __builtin_amdgcn_mfma_f32_16x16x32_f16(ah, bfr0, acch[i][0], 0, 0, 0);
      acch[i][1] = __builtin_amdgcn_mfma_f32_16x16x32_f16(ah, bfr1, acch[i][1], 0, 0, 0);
    }
  }

  #pragma unroll
  for (int j = 0; j < 2; j++) {
    int col = n0 + wn * 32 + j * 16 + fr;
    float scl = sc[col];
    #pragma unroll
    for (int i = 0; i < 4; i++) {
      #pragma unroll
      for (int r = 0; r < 4; r++) {
        int lrow = m0 + wm * 64 + i * 16 + ks * 4 + r;
        if (z > 0 && lrow >= mcount) continue;
        float v = acch[i][j][r] * scl;
        v = v * (1.0f / (1.0f + __expf(-v)));
        if (z > 0) CE[(size_t)(mbase + lrow) * 2048 + col] = (_Float16)v;
        else       CS[(size_t)lrow * 2048 + col] = (_Float16)v;
      }
    }
  }
}

// ===== fused shared-w2 + expert-w2 GEMM (NLOOP=1, z=0 dense->SO, z=1..8 scatter->RT) =====
__global__ __launch_bounds__(256) void k_mgemm_moe2(
    const _Float16* __restrict__ SMh, const _Float16* __restrict__ T1h,
    const _Float16* __restrict__ WhS, const _Float16* __restrict__ WhE,
    const float* __restrict__ scS, const float* __restrict__ scE,
    float* __restrict__ SO, float* __restrict__ RT,
    const int* __restrict__ offs, const int* __restrict__ tlist,
    const float* __restrict__ topp)
{
  int z = blockIdx.z;
  int mbase = 0, mcount = M_;
  const _Float16* Agh = SMh;
  const _Float16* Whb = WhS;
  const float* sc = scS;
  if (z > 0) {
    int e = z - 1;
    mbase = offs[e]; mcount = offs[e + 1] - mbase;
    Agh = T1h;
    Whb = WhE + (size_t)e * 1024 * 2048;
    sc = scE + (size_t)e * 1024;
  }
  int m0 = blockIdx.y * 128;
  if (z > 0 && m0 >= mcount) return;
  int n0 = blockIdx.x * 64;

  __shared__ __align__(16) _Float16 As[4][128][8];
  __shared__ __align__(16) _Float16 Qs[4][64][8];

  int tid = threadIdx.x;
  int lm  = tid >> 1;
  int kcA = (tid & 1) * 16;
  int lw  = tid >> 2;
  int kcW = (tid & 3) * 8;

  int am  = m0 + lm;
  int amc = (z > 0) ? ((am < mcount) ? am : (mcount - 1)) : am;
  int arow = (z > 0) ? (mbase + amc) : am;
  const _Float16* Arh = Agh + (size_t)arow * 2048;
  const _Float16* Wrh = Whb + (size_t)(n0 + lw) * 2048;

  int wv = tid >> 6, lane = tid & 63;
  int wm = wv >> 1, wn = wv & 1;
  int ks = lane >> 4, fr = lane & 15;

  f32x4 acch[4][2];
  #pragma unroll
  for (int i = 0; i < 4; i++)
    #pragma unroll
    for (int j = 0; j < 2; j++) acch[i][j] = (f32x4)0.f;

  for (int kt = 0; kt < 2048; kt += 32) {
    half8 a0 = *reinterpret_cast<const half8*>(Arh + kt + kcA);
    half8 a1 = *reinterpret_cast<const half8*>(Arh + kt + kcA + 8);
    half8 qv = *reinterpret_cast<const half8*>(Wrh + kt + kcW);
    __syncthreads();
    int sA = kcA >> 3;
    *reinterpret_cast<half8*>(&As[sA][lm][0])     = a0;
    *reinterpret_cast<half8*>(&As[sA + 1][lm][0]) = a1;
    *reinterpret_cast<half8*>(&Qs[kcW >> 3][lw][0]) = qv;
    __syncthreads();
    half8 bfr0 = *reinterpret_cast<half8*>(&Qs[ks][wn * 32 + fr][0]);
    half8 bfr1 = *reinterpret_cast<half8*>(&Qs[ks][wn * 32 + 16 + fr][0]);
    #pragma unroll
    for (int i = 0; i < 4; i++) {
      half8 ah = *reinterpret_cast<half8*>(&As[ks][wm * 64 + i * 16 + fr][0]);
      acch[i][0] = __builtin_amdgcn_mfma_f32_16x16x32_f16(ah, bfr0, acch[i][0], 0, 0, 0);
      acch[i][1] = __builtin_amdgcn_mfma_f32_16x16x32_f16(ah, bfr1, acch[i][1], 0, 0, 0);
    }
  }

  #pragma unroll
  for (int j = 0; j < 2; j++) {
    int col = n0 + wn * 32 + j * 16 + fr;
    float scl = sc[col];
    #pragma unroll
    for (int i = 0; i < 4; i++) {
      #pragma unroll
      for (int r = 0; r < 4; r++) {
        int lrow = m0 + wm * 64 + i * 16 + ks * 4 + r;
        if (z > 0 && lrow >= mcount) continue;
        float v = acch[i][j][r] * scl;
        if (z > 0) {
          int orow = tlist[mbase + lrow];
          RT[(size_t)orow * 1024 + col] = v * topp[orow];
        } else {
          SO[(size_t)lrow * 1024 + col] = v;
        }
      }
    }
  }
}

// ===== final add =====
__global__ __launch_bounds__(256) void k_final(const float* __restrict__ x1,
                                               const float* __restrict__ so,
                                               const float* __restrict__ rt,
                                               float* __restrict__ out) {
  #pragma clang fp contract(off)
  int i = blockIdx.x * 256 + threadIdx.x;
  float moe = so[i] + rt[i];
  out[i] = x1[i] + moe;
}

// ===== MFMA flash differential attention v5: BARRIER-FREE =====
// K/V fragments loaded DIRECTLY from global (pre-split layouts match the
// MFMA B-fragment shape); only the P transpose uses LDS (warp-private).
// Same fragment values in the same order as v4 -> bitwise identical output.
__global__ __launch_bounds__(256) void k_attn5(const float* __restrict__ q,
                                               const _Float16* __restrict__ khg,
                                               const _Float16* __restrict__ klg,
                                               const _Float16* __restrict__ vth,
                                               const _Float16* __restrict__ vtl,
                                               const float* __restrict__ lamp,
                                               _Float16* __restrict__ aoh,
                                               _Float16* __restrict__ aol)
{
  __shared__ __align__(16) _Float16 PH[4][16][72];
  __shared__ __align__(16) _Float16 PL[4][16][72];

  int bh = blockIdx.x;
  int b = bh >> 4, h = bh & 15;
  int y = blockIdx.y;
  int tq = (y < 8) ? (2 * y) : (31 - 2 * y);   // balanced pairing
  int t0 = tq * 64;
  int tid = threadIdx.x;
  int wm = tid >> 6, lane = tid & 63;
  int ks = lane >> 4, fr = lane & 15;
  size_t tokbase = (size_t)b * T_;
  float lam = lamp[0];

  // Q fragments (A layout): row = fr, k = s*32 + ks*8 + j
  half8 qh[2][2], ql[2][2];
  {
    const float* qr = q + (tokbase + t0 + wm * 16 + fr) * 2048 + h * 64;
    #pragma unroll
    for (int g = 0; g < 2; ++g)
      #pragma unroll
      for (int s = 0; s < 2; ++s) {
        const float* p = qr + g * 1024 + s * 32 + ks * 8;
        float4 x0 = *reinterpret_cast<const float4*>(p);
        float4 x1 = *reinterpret_cast<const float4*>(p + 4);
        float xv[8] = {x0.x,x0.y,x0.z,x0.w, x1.x,x1.y,x1.z,x1.w};
        half8 hh, ll;
        #pragma unroll
        for (int j = 0; j < 8; ++j) {
          _Float16 hv = (_Float16)xv[j];
          hh[j] = hv; ll[j] = (_Float16)((xv[j] - (float)hv) * 2048.0f);
        }
        qh[g][s] = hh; ql[g][s] = ll;
      }
  }

  f32x4 Oh[2][4], Ox[2][4];
  #pragma unroll
  for (int g = 0; g < 2; ++g)
    #pragma unroll
    for (int d = 0; d < 4; ++d) { Oh[g][d] = (f32x4)0.f; Ox[g][d] = (f32x4)0.f; }
  float mrun[2][4], lrun[2][4];
  #pragma unroll
  for (int g = 0; g < 2; ++g)
    #pragma unroll
    for (int r = 0; r < 4; ++r) { mrun[g][r] = -1e30f; lrun[g][r] = 0.f; }

  // per-head base pointers
  const size_t kstride = 2048;
  const _Float16* khb = khg + tokbase * kstride + h * 64;
  const _Float16* klb = klg + tokbase * kstride + h * 64;
  const _Float16* vhb = vth + ((size_t)b * 1024 + h * 64) * 1024;
  const _Float16* vlb = vtl + ((size_t)b * 1024 + h * 64) * 1024;

  for (int jt = 0; jt <= tq; ++jt) {
    int kv0 = jt * 64;
    bool diag = (jt == tq);
    #pragma unroll
    for (int g = 0; g < 2; ++g) {
      // ---- S strip: K fragments direct from global ----
      f32x4 Sh[4], Sx[4];
      #pragma unroll
      for (int kf = 0; kf < 4; ++kf) { Sh[kf] = (f32x4)0.f; Sx[kf] = (f32x4)0.f; }
      #pragma unroll
      for (int s = 0; s < 2; ++s) {
        #pragma unroll
        for (int kf = 0; kf < 4; ++kf) {
          size_t koff = (size_t)(kv0 + kf * 16 + fr) * kstride + g * 1024 + s * 32 + ks * 8;
          half8 kh = *reinterpret_cast<const half8*>(khb + koff);
          half8 kl = *reinterpret_cast<const half8*>(klb + koff);
          Sh[kf] = __builtin_amdgcn_mfma_f32_16x16x32_f16(qh[g][s], kh, Sh[kf], 0, 0, 0);
          Sx[kf] = __builtin_amdgcn_mfma_f32_16x16x32_f16(qh[g][s], kl, Sx[kf], 0, 0, 0);
          Sx[kf] = __builtin_amdgcn_mfma_f32_16x16x32_f16(ql[g][s], kh, Sx[kf], 0, 0, 0);
        }
      }
      float sv[4][4];
      #pragma unroll
      for (int kf = 0; kf < 4; ++kf)
        #pragma unroll
        for (int r = 0; r < 4; ++r) {
          float s_ = (Sh[kf][r] + Sx[kf][r] * (1.0f / 2048.0f)) * 0.125f;
          if (diag) {
            int row_abs = t0 + wm * 16 + ks * 4 + r;
            int col_abs = kv0 + kf * 16 + fr;
            if (col_abs > row_abs) s_ = -1e30f;
          }
          sv[kf][r] = s_;
        }
      #pragma unroll
      for (int r = 0; r < 4; ++r) {
        float tmax = fmaxf(fmaxf(sv[0][r], sv[1][r]), fmaxf(sv[2][r], sv[3][r]));
        #pragma unroll
        for (int msk = 1; msk < 16; msk <<= 1) tmax = fmaxf(tmax, __shfl_xor(tmax, msk));
        bool up = tmax > mrun[g][r];
        float mnew = up ? tmax : mrun[g][r];
        float e0 = __expf(sv[0][r] - mnew);
        float e1 = __expf(sv[1][r] - mnew);
        float e2 = __expf(sv[2][r] - mnew);
        float e3 = __expf(sv[3][r] - mnew);
        float rsum = (e0 + e1) + (e2 + e3);
        #pragma unroll
        for (int msk = 1; msk < 16; msk <<= 1) rsum += __shfl_xor(rsum, msk);
        if (up) {
          float scale = __expf(mrun[g][r] - tmax);
          lrun[g][r] = lrun[g][r] * scale + rsum;
          mrun[g][r] = tmax;
          #pragma unroll
          for (int df = 0; df < 4; ++df) { Oh[g][df][r] *= scale; Ox[g][df][r] *= scale; }
        } else {
          lrun[g][r] += rsum;
        }
        float ev[4] = {e0, e1, e2, e3};
        #pragma unroll
        for (int kf = 0; kf < 4; ++kf) {
          _Float16 ph = (_Float16)ev[kf];
          _Float16 pl = (_Float16)((ev[kf] - (float)ph) * 2048.0f);
          PH[wm][ks * 4 + r][kf * 16 + fr] = ph;
          PL[wm][ks * 4 + r][kf * 16 + fr] = pl;
        }
      }
      // ---- PV: V fragments direct from global (warp-private P in LDS) ----
      #pragma unroll
      for (int s = 0; s < 2; ++s) {
        half8 pah = *reinterpret_cast<half8*>(&PH[wm][fr][s * 32 + ks * 8]);
        half8 pal = *reinterpret_cast<half8*>(&PL[wm][fr][s * 32 + ks * 8]);
        #pragma unroll
        for (int df = 0; df < 4; ++df) {
          size_t voff = (size_t)(df * 16 + fr) * 1024 + kv0 + s * 32 + ks * 8;
          half8 vh = *reinterpret_cast<const half8*>(vhb + voff);
          half8 vl = *reinterpret_cast<const half8*>(vlb + voff);
          Oh[g][df] = __builtin_amdgcn_mfma_f32_16x16x32_f16(pah, vh, Oh[g][df], 0, 0, 0);
          Ox[g][df] = __builtin_amdgcn_mfma_f32_16x16x32_f16(pah, vl, Ox[g][df], 0, 0, 0);
          Ox[g][df] = __builtin_amdgcn_mfma_f32_16x16x32_f16(pal, vh, Ox[g][df], 0, 0, 0);
        }
      }
    }
  }

  #pragma unroll
  for (int df = 0; df < 4; ++df) {
    #pragma unroll
    for (int r = 0; r < 4; ++r) {
      int row_abs = t0 + wm * 16 + ks * 4 + r;
      int d = df * 16 + fr;
      float o1 = (Oh[0][df][r] + Ox[0][df][r] * (1.0f / 2048.0f)) / lrun[0][r];
      float o2 = (Oh[1][df][r] + Ox[1][df][r] * (1.0f / 2048.0f)) / lrun[1][r];
      float oo = o1 - lam * o2;
      size_t idx = (tokbase + row_abs) * 1024 + h * 64 + d;
      _Float16 hv = (_Float16)oo;
      aoh[idx] = hv;
      aol[idx] = (_Float16)((oo - (float)hv) * 2048.0f);
    }
  }
}

// ===== router =====
__global__ __launch_bounds__(256) void k_router(const float* __restrict__ hm,
                                                const float* __restrict__ rw,
                                                int* __restrict__ idx,
                                                float* __restrict__ topp)
{
  #pragma clang fp contract(off)
  int tid = threadIdx.x;
  int tg = tid >> 3, e = tid & 7;
  int m = blockIdx.x * 32 + tg;
  const float* hr = hm + (size_t)m * 1024;
  const float* wr = rw + (size_t)e * 1024;
  float l = 0.f;
  for (int dd = 0; dd < 1024; ++dd) l = __builtin_fmaf(hr[dd], wr[dd], l);
  float mx = l;
  #pragma unroll
  for (int off = 1; off < 8; off <<= 1) mx = fmaxf(mx, __shfl_xor(mx, off, 8));
  float p = __expf(l - mx);
  float den = p;
  #pragma unroll
  for (int off = 1; off < 8; off <<= 1) den += __shfl_xor(den, off, 8);
  float prob = p / den;
  float pm = prob;
  #pragma unroll
  for (int off = 1; off < 8; off <<= 1) pm = fmaxf(pm, __shfl_xor(pm, off, 8));
  unsigned long long ball = __ballot(prob == pm);
  int grp = (tid & 63) >> 3;
  int first = __ffsll((unsigned long long)((ball >> (grp * 8)) & 0xFFull)) - 1;
  if (e == 0) { idx[m] = first; topp[m] = pm; }
}

// ===== deterministic token compaction =====
__global__ __launch_bounds__(512) void k_route_fill(const int* __restrict__ idx,
                                                    int* __restrict__ offs,
                                                    int* __restrict__ tlist)
{
  __shared__ int cnt[8];
  __shared__ int off[9];
  int w = threadIdx.x >> 6, lane = threadIdx.x & 63;
  int total = 0;
  for (int it = 0; it < M_ / 64; ++it) {
    int tok = it * 64 + lane;
    unsigned long long m = __ballot(idx[tok] == w);
    total += __popcll(m);
  }
  if (lane == 0) cnt[w] = total;
  __syncthreads();
  if (threadIdx.x == 0) {
    int o = 0;
    for (int e = 0; e < 8; ++e) { off[e] = o; o += cnt[e]; }
    off[8] = o;
    for (int e = 0; e < 9; ++e) offs[e] = off[e];
  }
  __syncthreads();
  int base = off[w];
  for (int it = 0; it < M_ / 64; ++it) {
    int tok = it * 64 + lane;
    bool sel = (idx[tok] == w);
    unsigned long long m = __ballot(sel);
    if (sel) {
      int pos = base + __popcll(m & ((1ull << lane) - 1ull));
      tlist[pos] = tok;
    }
    base += __popcll(m);
  }
}

extern "C" void kernel_launch(void* const* d_in, const int* in_sizes, int n_in,
                              void* d_out, int out_size, void* d_ws, size_t ws_size,
                              hipStream_t stream) {
  const float* x   = (const float*)d_in[0];
  const float* Wq  = (const float*)d_in[2];
  const float* Wk  = (const float*)d_in[3];
  const float* Wv  = (const float*)d_in[4];
  const float* Wo  = (const float*)d_in[5];
  const float* lq  = (const float*)d_in[6];
  const float* lk  = (const float*)d_in[7];
  const float* qng = (const float*)d_in[8];
  const float* qnb = (const float*)d_in[9];
  const float* kng = (const float*)d_in[10];
  const float* knb = (const float*)d_in[11];
  const float* ag  = (const float*)d_in[12];
  const float* ab  = (const float*)d_in[13];
  const float* fg  = (const float*)d_in[14];
  const float* fb  = (const float*)d_in[15];
  const float* mg  = (const float*)d_in[16];
  const float* mb  = (const float*)d_in[17];
  const float* sw1 = (const float*)d_in[18];
  const float* sw2 = (const float*)d_in[19];
  const float* ew1 = (const float*)d_in[20];
  const float* ew2 = (const float*)d_in[21];
  const float* rw  = (const float*)d_in[22];

  float* ws = (float*)d_ws;
  size_t o = 0;
  float* scWq = ws + o; o += 2048;
  float* scWk = ws + o; o += 2048;
  float* scWv = ws + o; o += 1024;
  float* scWo = ws + o; o += 1024;
  float* scS1 = ws + o; o += 2048;
  float* scS2 = ws + o; o += 1024;
  float* scE1 = ws + o; o += 8 * 2048;
  float* scE2 = ws + o; o += 8 * 1024;
  float* lam  = ws + o; o += 16;
  float* TOPP = ws + o; o += 2048;
  int*   IDX  = (int*)(ws + o); o += 2048;
  int*   OFFS = (int*)(ws + o); o += 16;
  int*   TLIST= (int*)(ws + o); o += 2048;
  o = (o + 15) & ~(size_t)15;

  _Float16* QWq = (_Float16*)(ws + o); o += 1024 * 1024;
  _Float16* QWk = (_Float16*)(ws + o); o += 1024 * 1024;
  _Float16* QWv = (_Float16*)(ws + o); o += 512 * 1024;
  _Float16* QWo = (_Float16*)(ws + o); o += 512 * 1024;
  _Float16* QS1 = (_Float16*)(ws + o); o += 1024 * 1024;
  _Float16* QS2 = (_Float16*)(ws + o); o += 1024 * 1024;
  _Float16* QE1 = (_Float16*)(ws + o); o += 8 * 1024 * 1024;
  _Float16* QE2 = (_Float16*)(ws + o); o += 8 * 1024 * 1024;

  float* RA = ws + o; o += 2 * 1024 * 1024;
  _Float16* H1h = (_Float16*)RA;
  _Float16* H1l = (_Float16*)(RA + 1024 * 1024);
  _Float16* SMh = (_Float16*)RA;
  float* RB = ws + o; o += 2 * 1024 * 1024;
  _Float16* AOh = (_Float16*)RB;
  _Float16* AOl = (_Float16*)(RB + 1024 * 1024);
  _Float16* HMh = (_Float16*)RB;
  _Float16* T1h = (_Float16*)(ws + o); o += 2 * 1024 * 1024;

  const size_t MQ = (size_t)M_ * 2048;
  float* QP = ws + o; o += MQ;
  float* KP = ws + o; o += MQ;
  _Float16* KHg = (_Float16*)(ws + o); o += 2 * 1024 * 1024;
  _Float16* KLg = (_Float16*)(ws + o); o += 2 * 1024 * 1024;
  _Float16* VTH = (_Float16*)(ws + o); o += 1024 * 1024;
  _Float16* VTL = (_Float16*)(ws + o); o += 1024 * 1024;

  float* X1 = QP;
  float* HM = QP + MQ / 2;
  float* SO = KP;
  float* RT = (float*)KHg;

  // scales + prequant + lambda (one launch)
  k_scaleq_all<<<33793, 64, 0, stream>>>(Wq, Wk, Wv, Wo, sw1, sw2, ew1, ew2, lq, lk,
                                         scWq, scWk, scWv, scWo, scS1, scS2, scE1, scE2,
                                         QWq, QWk, QWv, QWo, QS1, QS2, QE1, QE2, lam);

  // attention block (router path: DUAL)
  k_layernorm_split<<<M_, 256, 0, stream>>>(x, ag, ab, H1h, H1l, 1024);
  k_mgemm_qkv<<<dim3(80,16), 256, 0, stream>>>(H1h, H1l, QWq, QWk, QWv, scWq, scWk, scWv, QP, KP, VTH, VTL);
  k_lnqk<<<2 * M_, 256, 0, stream>>>(QP, qng, qnb, KP, kng, knb, KHg, KLg);
  k_attn5<<<dim3(32, 16), 256, 0, stream>>>(QP, KHg, KLg, VTH, VTL, lam, AOh, AOl);
  k_mgemm<2,0,1><<<dim3(16,16), 256, 0, stream>>>(AOh, AOl, 1024, QWo, scWo, X1, nullptr, nullptr, 1024, 1024, 1024, x, nullptr, nullptr, nullptr, nullptr);

  // MoE block
  k_lnln<<<M_, 256, 0, stream>>>(X1, fg, fb, mg, mb, HM, HMh);
  k_router<<<M_ / 32, 256, 0, stream>>>(HM, rw, IDX, TOPP);
  k_route_fill<<<1, 512, 0, stream>>>(IDX, OFFS, TLIST);

  // fused MoE GEMMs (NLOOP=1 — occupancy wins over A-reuse here)
  k_mgemm_moe1<<<dim3(32,16,9), 256, 0, stream>>>(HMh, QS1, QE1, scS1, scE1, SMh, T1h, OFFS, TLIST);
  k_mgemm_moe2<<<dim3(16,16,9), 256, 0, stream>>>(SMh, T1h, QS2, QE2, scS2, scE2, SO, RT, OFFS, TLIST, TOPP);

  k_final<<<8192, 256, 0, stream>>>(X1, SO, RT, (float*)d_out);
}

// Round 18
// 531.223 us; speedup vs baseline: 1.0442x; 1.0442x over previous
//
#include <hip/hip_runtime.h>
#include <hip/hip_bf16.h>

#define B_ 2
#define T_ 1024
#define D_ 1024
#define H_ 16
#define DH_ 64
#define F_ 2048
#define E_ 8
#define M_ 2048   // B*T tokens

typedef _Float16 half8 __attribute__((ext_vector_type(8)));
typedef _Float16 half4v __attribute__((ext_vector_type(4)));
typedef float f32x4 __attribute__((ext_vector_type(4)));

// ===== numpy-style pairwise sum of a[0..K), K in {1024, 2048}, one wave =====
template<bool ABS>
__device__ __forceinline__ float np_pairwise_wave(const float* a, int K, int lane) {
  int nb = K >> 7;
  float s = 0.f;
  if (lane < nb) {
    const float* p = a + (lane << 7);
    float r[8];
    #pragma unroll
    for (int j = 0; j < 8; ++j) r[j] = ABS ? fabsf(p[j]) : p[j];
    for (int i = 8; i < 128; i += 8)
      #pragma unroll
      for (int j = 0; j < 8; ++j) r[j] += ABS ? fabsf(p[i + j]) : p[i + j];
    s = ((r[0] + r[1]) + (r[2] + r[3])) + ((r[4] + r[5]) + (r[6] + r[7]));
  }
  for (int off = 1; off < nb; off <<= 1) s += __shfl_xor(s, off);
  return __shfl(s, 0);
}

// ===== ALL weight scales + prequant + lambda in ONE launch =====
__global__ __launch_bounds__(64) void k_scaleq_all(
    const float* __restrict__ Wq, const float* __restrict__ Wk,
    const float* __restrict__ Wv, const float* __restrict__ Wo,
    const float* __restrict__ sw1, const float* __restrict__ sw2,
    const float* __restrict__ ew1, const float* __restrict__ ew2,
    const float* __restrict__ lq, const float* __restrict__ lk,
    float* __restrict__ scWq, float* __restrict__ scWk,
    float* __restrict__ scWv, float* __restrict__ scWo,
    float* __restrict__ scS1, float* __restrict__ scS2,
    float* __restrict__ scE1, float* __restrict__ scE2,
    _Float16* __restrict__ QWq, _Float16* __restrict__ QWk,
    _Float16* __restrict__ QWv, _Float16* __restrict__ QWo,
    _Float16* __restrict__ QS1, _Float16* __restrict__ QS2,
    _Float16* __restrict__ QE1, _Float16* __restrict__ QE2,
    float* __restrict__ lam)
{
  int r = blockIdx.x, lane = threadIdx.x;
  if (r == 33792) {   // lambda block
    float mq = np_pairwise_wave<false>(lq, 1024, lane) / 1024.0f;
    float mk = np_pairwise_wave<false>(lk, 1024, lane) / 1024.0f;
    if (lane == 0) {
      float l = expf(mq - mk);
      lam[0] = fminf(2.0f, fmaxf(0.1f, l));
    }
    return;
  }
  const float* W; float* sc; _Float16* qo; int K; int rr;
  if      (r < 2048)  { W = Wq;  sc = scWq; qo = QWq; K = 1024; rr = r; }
  else if (r < 4096)  { W = Wk;  sc = scWk; qo = QWk; K = 1024; rr = r - 2048; }
  else if (r < 5120)  { W = Wv;  sc = scWv; qo = QWv; K = 1024; rr = r - 4096; }
  else if (r < 6144)  { W = Wo;  sc = scWo; qo = QWo; K = 1024; rr = r - 5120; }
  else if (r < 8192)  { W = sw1; sc = scS1; qo = QS1; K = 1024; rr = r - 6144; }
  else if (r < 9216)  { W = sw2; sc = scS2; qo = QS2; K = 2048; rr = r - 8192; }
  else if (r < 25600) { W = ew1; sc = scE1; qo = QE1; K = 1024; rr = r - 9216; }
  else                { W = ew2; sc = scE2; qo = QE2; K = 2048; rr = r - 25600; }
  const float* row = W + (size_t)rr * K;
  float S = np_pairwise_wave<true>(row, K, lane);
  float s = fmaxf(S / (float)K, 1e-5f);
  if (lane == 0) sc[rr] = s;
  _Float16* dst = qo + (size_t)rr * K;
  for (int k = lane * 4; k < K; k += 256) {
    float4 w = *reinterpret_cast<const float4*>(row + k);
    float wv[4] = {w.x, w.y, w.z, w.w};
    half4v q4;
    #pragma unroll
    for (int j = 0; j < 4; ++j) {
      float q = rintf(wv[j] / s);
      q = fminf(1.f, fmaxf(-1.f, q));
      q4[j] = (_Float16)q;
    }
    *reinterpret_cast<half4v*>(dst + k) = q4;
  }
}

// ===== layernorm f32 -> fp16 hi/lo split (for x -> H1) =====
__global__ __launch_bounds__(256) void k_layernorm_split(const float* __restrict__ in,
                                                         const float* __restrict__ g,
                                                         const float* __restrict__ b,
                                                         _Float16* __restrict__ oh,
                                                         _Float16* __restrict__ ol, int Dd) {
  #pragma clang fp contract(off)
  __shared__ float row[2048];
  __shared__ float sq[2048];
  __shared__ float stat[2];
  int m = blockIdx.x, tid = threadIdx.x;
  const float* src = in + (size_t)m * Dd;
  for (int d = tid; d < Dd; d += 256) row[d] = src[d];
  __syncthreads();
  if (tid < 64) {
    float S = np_pairwise_wave<false>(row, Dd, tid);
    if (tid == 0) stat[0] = S;
  }
  __syncthreads();
  float mean = stat[0] / (float)Dd;
  for (int d = tid; d < Dd; d += 256) { float t = row[d] - mean; sq[d] = t * t; }
  __syncthreads();
  if (tid < 64) {
    float S = np_pairwise_wave<false>(sq, Dd, tid);
    if (tid == 0) stat[1] = S;
  }
  __syncthreads();
  float var = stat[1] / (float)Dd;
  float rs = 1.0f / sqrtf(var + 1e-5f);
  #pragma unroll 1
  for (int d = tid; d < Dd; d += 256) {
    float t = row[d] - mean;
    float u = t * rs;
    float v = u * g[d];
    float w = v + b[d];
    _Float16 hv = (_Float16)w;
    oh[(size_t)m * Dd + d] = hv;
    ol[(size_t)m * Dd + d] = (_Float16)((w - (float)hv) * 2048.0f);
  }
}

// ===== fused Q-LN (f32 in-place) + K-LN (split) in one launch =====
__global__ __launch_bounds__(256) void k_lnqk(float* __restrict__ QP,
                                              const float* __restrict__ qg, const float* __restrict__ qb,
                                              const float* __restrict__ KP,
                                              const float* __restrict__ kg, const float* __restrict__ kb,
                                              _Float16* __restrict__ khg, _Float16* __restrict__ klg) {
  #pragma clang fp contract(off)
  __shared__ float row[2048];
  __shared__ float sq[2048];
  __shared__ float stat[2];
  int blk = blockIdx.x, tid = threadIdx.x;
  bool isQ = blk < 2048;
  int m = isQ ? blk : (blk - 2048);
  const float* src = (isQ ? (const float*)QP : KP) + (size_t)m * 2048;
  for (int d = tid; d < 2048; d += 256) row[d] = src[d];
  __syncthreads();
  if (tid < 64) {
    float S = np_pairwise_wave<false>(row, 2048, tid);
    if (tid == 0) stat[0] = S;
  }
  __syncthreads();
  float mean = stat[0] / 2048.0f;
  for (int d = tid; d < 2048; d += 256) { float t = row[d] - mean; sq[d] = t * t; }
  __syncthreads();
  if (tid < 64) {
    float S = np_pairwise_wave<false>(sq, 2048, tid);
    if (tid == 0) stat[1] = S;
  }
  __syncthreads();
  float var = stat[1] / 2048.0f;
  float rs = 1.0f / sqrtf(var + 1e-5f);
  if (isQ) {
    float* dst = QP + (size_t)m * 2048;
    for (int d = tid; d < 2048; d += 256) {
      float t = row[d] - mean;
      float u = t * rs;
      float v = u * qg[d];
      dst[d] = v + qb[d];
    }
  } else {
    #pragma unroll 1
    for (int d = tid; d < 2048; d += 256) {
      float t = row[d] - mean;
      float u = t * rs;
      float v = u * kg[d];
      float w = v + kb[d];
      _Float16 hv = (_Float16)w;
      khg[(size_t)m * 2048 + d] = hv;
      klg[(size_t)m * 2048 + d] = (_Float16)((w - (float)hv) * 2048.0f);
    }
  }
}

// ===== fused double layernorm =====
__global__ __launch_bounds__(256) void k_lnln(const float* __restrict__ in,
                                              const float* __restrict__ g1, const float* __restrict__ b1,
                                              const float* __restrict__ g2, const float* __restrict__ b2,
                                              float* __restrict__ outf,
                                              _Float16* __restrict__ outh) {
  #pragma clang fp contract(off)
  __shared__ float row[1024];
  __shared__ float tmp[1024];
  __shared__ float stat[2];
  int m = blockIdx.x, tid = threadIdx.x;
  const float* src = in + (size_t)m * 1024;
  for (int d = tid; d < 1024; d += 256) row[d] = src[d];
  __syncthreads();
  if (tid < 64) { float S = np_pairwise_wave<false>(row, 1024, tid); if (tid == 0) stat[0] = S; }
  __syncthreads();
  float mean = stat[0] / 1024.0f;
  for (int d = tid; d < 1024; d += 256) { float t = row[d] - mean; tmp[d] = t * t; }
  __syncthreads();
  if (tid < 64) { float S = np_pairwise_wave<false>(tmp, 1024, tid); if (tid == 0) stat[1] = S; }
  __syncthreads();
  float rs = 1.0f / sqrtf(stat[1] / 1024.0f + 1e-5f);
  for (int d = tid; d < 1024; d += 256) {
    float t = row[d] - mean;
    float u = t * rs;
    float v = u * g1[d];
    tmp[d] = v + b1[d];
  }
  __syncthreads();
  if (tid < 64) { float S = np_pairwise_wave<false>(tmp, 1024, tid); if (tid == 0) stat[0] = S; }
  __syncthreads();
  float mean2 = stat[0] / 1024.0f;
  for (int d = tid; d < 1024; d += 256) { float t = tmp[d] - mean2; row[d] = t * t; }
  __syncthreads();
  if (tid < 64) { float S = np_pairwise_wave<false>(row, 1024, tid); if (tid == 0) stat[1] = S; }
  __syncthreads();
  float rs2 = 1.0f / sqrtf(stat[1] / 1024.0f + 1e-5f);
  for (int d = tid; d < 1024; d += 256) {
    float t = tmp[d] - mean2;
    float u = t * rs2;
    float v = u * g2[d];
    float w = v + b2[d];
    outf[(size_t)m * 1024 + d] = w;
    outh[(size_t)m * 1024 + d] = (_Float16)w;
  }
}

// ===== generic MFMA GEMM (used for Wo only) =====
template<int EPI, int XM, int DUAL>
__global__ __launch_bounds__(256) void k_mgemm(
    const _Float16* __restrict__ Agh, const _Float16* __restrict__ Agl, int lda,
    const _Float16* __restrict__ Wh, const float* __restrict__ scf,
    float* __restrict__ Cout, _Float16* __restrict__ Ch, _Float16* __restrict__ Ch2,
    int ldc, int N, int K,
    const float* __restrict__ res, const float* __restrict__ add2,
    const int* __restrict__ offs, const int* __restrict__ tlist,
    const float* __restrict__ topp)
{
  int e = XM ? blockIdx.z : 0;
  int mbase = 0, mcount = M_;
  const float* sc = scf;
  const _Float16* Whb = Wh;
  if (XM) {
    mbase = offs[e]; mcount = offs[e + 1] - mbase;
    Whb = Wh + (size_t)e * N * K;
    sc = scf + (size_t)e * N;
  }
  int m0 = blockIdx.y * 128;
  if (XM && m0 >= mcount) return;
  int n0 = blockIdx.x * 64;

  __shared__ __align__(16) _Float16 As[4][128][8];
  __shared__ __align__(16) _Float16 Als[DUAL ? 4 : 1][128][8];
  __shared__ __align__(16) _Float16 Qs[4][64][8];

  int tid = threadIdx.x;
  int lm  = tid >> 1;
  int kcA = (tid & 1) * 16;
  int lw  = tid >> 2;
  int kcW = (tid & 3) * 8;

  int am  = m0 + lm;
  int amc = XM ? ((am < mcount) ? am : (mcount - 1)) : am;
  int arow;
  if (XM == 1)      arow = tlist[mbase + amc];
  else if (XM == 2) arow = mbase + amc;
  else              arow = am;
  const _Float16* Arh = Agh + (size_t)arow * lda;
  const _Float16* Arl = DUAL ? (Agl + (size_t)arow * lda) : nullptr;
  const _Float16* Wrh = Whb + (size_t)(n0 + lw) * K;

  int wv = tid >> 6, lane = tid & 63;
  int wm = wv >> 1, wn = wv & 1;
  int ks = lane >> 4, fr = lane & 15;

  f32x4 acch[4][2], accl[4][2];
  #pragma unroll
  for (int i = 0; i < 4; i++)
    #pragma unroll
    for (int j = 0; j < 2; j++) { acch[i][j] = (f32x4)0.f; accl[i][j] = (f32x4)0.f; }

  for (int kt = 0; kt < K; kt += 32) {
    half8 a0 = *reinterpret_cast<const half8*>(Arh + kt + kcA);
    half8 a1 = *reinterpret_cast<const half8*>(Arh + kt + kcA + 8);
    half8 b0, b1;
    if (DUAL) {
      b0 = *reinterpret_cast<const half8*>(Arl + kt + kcA);
      b1 = *reinterpret_cast<const half8*>(Arl + kt + kcA + 8);
    }
    half8 qv = *reinterpret_cast<const half8*>(Wrh + kt + kcW);
    __syncthreads();
    int sA = kcA >> 3;
    *reinterpret_cast<half8*>(&As[sA][lm][0])     = a0;
    *reinterpret_cast<half8*>(&As[sA + 1][lm][0]) = a1;
    if (DUAL) {
      *reinterpret_cast<half8*>(&Als[sA][lm][0])     = b0;
      *reinterpret_cast<half8*>(&Als[sA + 1][lm][0]) = b1;
    }
    *reinterpret_cast<half8*>(&Qs[kcW >> 3][lw][0]) = qv;
    __syncthreads();
    half8 bfr0 = *reinterpret_cast<half8*>(&Qs[ks][wn * 32 + fr][0]);
    half8 bfr1 = *reinterpret_cast<half8*>(&Qs[ks][wn * 32 + 16 + fr][0]);
    #pragma unroll
    for (int i = 0; i < 4; i++) {
      half8 ah = *reinterpret_cast<half8*>(&As[ks][wm * 64 + i * 16 + fr][0]);
      acch[i][0] = __builtin_amdgcn_mfma_f32_16x16x32_f16(ah, bfr0, acch[i][0], 0, 0, 0);
      acch[i][1] = __builtin_amdgcn_mfma_f32_16x16x32_f16(ah, bfr1, acch[i][1], 0, 0, 0);
      if (DUAL) {
        half8 al = *reinterpret_cast<half8*>(&Als[ks][wm * 64 + i * 16 + fr][0]);
        accl[i][0] = __builtin_amdgcn_mfma_f32_16x16x32_f16(al, bfr0, accl[i][0], 0, 0, 0);
        accl[i][1] = __builtin_amdgcn_mfma_f32_16x16x32_f16(al, bfr1, accl[i][1], 0, 0, 0);
      }
    }
  }

  #pragma unroll
  for (int j = 0; j < 2; j++) {
    int col = n0 + wn * 32 + j * 16 + fr;
    float scl = sc[col];
    #pragma unroll
    for (int i = 0; i < 4; i++) {
      #pragma unroll
      for (int r = 0; r < 4; r++) {
        int lrow = m0 + wm * 64 + i * 16 + ks * 4 + r;
        if (XM && lrow >= mcount) continue;
        int orow;
        if (XM == 1)      orow = mbase + lrow;
        else if (XM == 2) orow = tlist[mbase + lrow];
        else              orow = lrow;
        float v = acch[i][j][r];
        if (DUAL) v += accl[i][j][r] * (1.0f / 2048.0f);
        v *= scl;
        if (EPI == 1) {
          v = v * (1.0f / (1.0f + __expf(-v)));
          Ch[(size_t)orow * ldc + col] = (_Float16)v;
        } else if (EPI == 2) {
          Cout[(size_t)orow * ldc + col] = res[(size_t)orow * ldc + col] + v;
        } else {
          Cout[(size_t)orow * ldc + col] = v;
        }
      }
    }
  }
}

// ===== fused Q+K+V GEMM (DUAL, one launch, 80 n-tiles) =====
__global__ __launch_bounds__(256) void k_mgemm_qkv(
    const _Float16* __restrict__ Agh, const _Float16* __restrict__ Agl,
    const _Float16* __restrict__ WQ_, const _Float16* __restrict__ WK_, const _Float16* __restrict__ WV_,
    const float* __restrict__ scq, const float* __restrict__ sck, const float* __restrict__ scv,
    float* __restrict__ Cq, float* __restrict__ Ck,
    _Float16* __restrict__ Vth, _Float16* __restrict__ Vtl)
{
  int nt = blockIdx.x;
  int sel = (nt < 32) ? 0 : (nt < 64 ? 1 : 2);
  int n0 = ((sel == 0) ? nt : (sel == 1) ? (nt - 32) : (nt - 64)) * 64;
  const _Float16* Wh = (sel == 0) ? WQ_ : (sel == 1) ? WK_ : WV_;
  const float* sc = (sel == 0) ? scq : (sel == 1) ? sck : scv;
  int m0 = blockIdx.y * 128;

  __shared__ __align__(16) _Float16 As[4][128][8];
  __shared__ __align__(16) _Float16 Als[4][128][8];
  __shared__ __align__(16) _Float16 Qs[4][64][8];

  int tid = threadIdx.x;
  int lm  = tid >> 1;
  int kcA = (tid & 1) * 16;
  int lw  = tid >> 2;
  int kcW = (tid & 3) * 8;

  const _Float16* Arh = Agh + (size_t)(m0 + lm) * 1024;
  const _Float16* Arl = Agl + (size_t)(m0 + lm) * 1024;
  const _Float16* Wrh = Wh + (size_t)(n0 + lw) * 1024;

  int wv = tid >> 6, lane = tid & 63;
  int wm = wv >> 1, wn = wv & 1;
  int ks = lane >> 4, fr = lane & 15;

  f32x4 acch[4][2], accl[4][2];
  #pragma unroll
  for (int i = 0; i < 4; i++)
    #pragma unroll
    for (int j = 0; j < 2; j++) { acch[i][j] = (f32x4)0.f; accl[i][j] = (f32x4)0.f; }

  for (int kt = 0; kt < 1024; kt += 32) {
    half8 a0 = *reinterpret_cast<const half8*>(Arh + kt + kcA);
    half8 a1 = *reinterpret_cast<const half8*>(Arh + kt + kcA + 8);
    half8 b0 = *reinterpret_cast<const half8*>(Arl + kt + kcA);
    half8 b1 = *reinterpret_cast<const half8*>(Arl + kt + kcA + 8);
    half8 qv = *reinterpret_cast<const half8*>(Wrh + kt + kcW);
    __syncthreads();
    int sA = kcA >> 3;
    *reinterpret_cast<half8*>(&As[sA][lm][0])      = a0;
    *reinterpret_cast<half8*>(&As[sA + 1][lm][0])  = a1;
    *reinterpret_cast<half8*>(&Als[sA][lm][0])     = b0;
    *reinterpret_cast<half8*>(&Als[sA + 1][lm][0]) = b1;
    *reinterpret_cast<half8*>(&Qs[kcW >> 3][lw][0]) = qv;
    __syncthreads();
    half8 bfr0 = *reinterpret_cast<half8*>(&Qs[ks][wn * 32 + fr][0]);
    half8 bfr1 = *reinterpret_cast<half8*>(&Qs[ks][wn * 32 + 16 + fr][0]);
    #pragma unroll
    for (int i = 0; i < 4; i++) {
      half8 ah = *reinterpret_cast<half8*>(&As[ks][wm * 64 + i * 16 + fr][0]);
      half8 al = *reinterpret_cast<half8*>(&Als[ks][wm * 64 + i * 16 + fr][0]);
      acch[i][0] = __builtin_amdgcn_mfma_f32_16x16x32_f16(ah, bfr0, acch[i][0], 0, 0, 0);
      acch[i][1] = __builtin_amdgcn_mfma_f32_16x16x32_f16(ah, bfr1, acch[i][1], 0, 0, 0);
      accl[i][0] = __builtin_amdgcn_mfma_f32_16x16x32_f16(al, bfr0, accl[i][0], 0, 0, 0);
      accl[i][1] = __builtin_amdgcn_mfma_f32_16x16x32_f16(al, bfr1, accl[i][1], 0, 0, 0);
    }
  }

  #pragma unroll
  for (int j = 0; j < 2; j++) {
    int col = n0 + wn * 32 + j * 16 + fr;
    float scl = sc[col];
    #pragma unroll
    for (int i = 0; i < 4; i++) {
      #pragma unroll
      for (int r = 0; r < 4; r++) {
        int orow = m0 + wm * 64 + i * 16 + ks * 4 + r;
        float v = (acch[i][j][r] + accl[i][j][r] * (1.0f / 2048.0f)) * scl;
        if (sel == 0) {
          Cq[(size_t)orow * 2048 + col] = v;
        } else if (sel == 1) {
          Ck[(size_t)orow * 2048 + col] = v;
        } else {
          int bb = orow >> 10, tok = orow & 1023;
          size_t vidx = ((size_t)(bb << 10) + col) * 1024 + tok;
          _Float16 hv = (_Float16)v;
          Vth[vidx] = hv;
          Vtl[vidx] = (_Float16)((v - (float)hv) * 2048.0f);
        }
      }
    }
  }
}

// ===== fused shared-w1 + expert-w1 GEMM (NLOOP=1, z=0 dense, z=1..8 expert) =====
__global__ __launch_bounds__(256) void k_mgemm_moe1(
    const _Float16* __restrict__ Agh,
    const _Float16* __restrict__ WhS, const _Float16* __restrict__ WhE,
    const float* __restrict__ scS, const float* __restrict__ scE,
    _Float16* __restrict__ CS, _Float16* __restrict__ CE,
    const int* __restrict__ offs, const int* __restrict__ tlist)
{
  int z = blockIdx.z;
  int mbase = 0, mcount = M_;
  const _Float16* Whb = WhS;
  const float* sc = scS;
  if (z > 0) {
    int e = z - 1;
    mbase = offs[e]; mcount = offs[e + 1] - mbase;
    Whb = WhE + (size_t)e * 2048 * 1024;
    sc = scE + (size_t)e * 2048;
  }
  int m0 = blockIdx.y * 128;
  if (z > 0 && m0 >= mcount) return;
  int n0 = blockIdx.x * 64;

  __shared__ __align__(16) _Float16 As[4][128][8];
  __shared__ __align__(16) _Float16 Qs[4][64][8];

  int tid = threadIdx.x;
  int lm  = tid >> 1;
  int kcA = (tid & 1) * 16;
  int lw  = tid >> 2;
  int kcW = (tid & 3) * 8;

  int am  = m0 + lm;
  int amc = (z > 0) ? ((am < mcount) ? am : (mcount - 1)) : am;
  int arow = (z > 0) ? tlist[mbase + amc] : am;
  const _Float16* Arh = Agh + (size_t)arow * 1024;
  const _Float16* Wrh = Whb + (size_t)(n0 + lw) * 1024;

  int wv = tid >> 6, lane = tid & 63;
  int wm = wv >> 1, wn = wv & 1;
  int ks = lane >> 4, fr = lane & 15;

  f32x4 acch[4][2];
  #pragma unroll
  for (int i = 0; i < 4; i++)
    #pragma unroll
    for (int j = 0; j < 2; j++) acch[i][j] = (f32x4)0.f;

  for (int kt = 0; kt < 1024; kt += 32) {
    half8 a0 = *reinterpret_cast<const half8*>(Arh + kt + kcA);
    half8 a1 = *reinterpret_cast<const half8*>(Arh + kt + kcA + 8);
    half8 qv = *reinterpret_cast<const half8*>(Wrh + kt + kcW);
    __syncthreads();
    int sA = kcA >> 3;
    *reinterpret_cast<half8*>(&As[sA][lm][0])     = a0;
    *reinterpret_cast<half8*>(&As[sA + 1][lm][0]) = a1;
    *reinterpret_cast<half8*>(&Qs[kcW >> 3][lw][0]) = qv;
    __syncthreads();
    half8 bfr0 = *reinterpret_cast<half8*>(&Qs[ks][wn * 32 + fr][0]);
    half8 bfr1 = *reinterpret_cast<half8*>(&Qs[ks][wn * 32 + 16 + fr][0]);
    #pragma unroll
    for (int i = 0; i < 4; i++) {
      half8 ah = *reinterpret_cast<half8*>(&As[ks][wm * 64 + i * 16 + fr][0]);
      acch[i][0] = __builtin_amdgcn_mfma_f32_16x16x32_f16(ah, bfr0, acch[i][0], 0, 0, 0);
      acch[i][1] = __builtin_amdgcn_mfma_f32_16x16x32_f16(ah, bfr1, acch[i][1], 0, 0, 0);
    }
  }

  #pragma unroll
  for (int j = 0; j < 2; j++) {
    int col = n0 + wn * 32 + j * 16 + fr;
    float scl = sc[col];
    #pragma unroll
    for (int i = 0; i < 4; i++) {
      #pragma unroll
      for (int r = 0; r < 4; r++) {
        int lrow = m0 + wm * 64 + i * 16 + ks * 4 + r;
        if (z > 0 && lrow >= mcount) continue;
        float v = acch[i][j][r] * scl;
        v = v * (1.0f / (1.0f + __expf(-v)));
        if (z > 0) CE[(size_t)(mbase + lrow) * 2048 + col] = (_Float16)v;
        else       CS[(size_t)lrow * 2048 + col] = (_Float16)v;
      }
    }
  }
}

// ===== fused shared-w2 + expert-w2 GEMM (NLOOP=1, z=0 dense->SO, z=1..8 scatter->RT) =====
__global__ __launch_bounds__(256) void k_mgemm_moe2(
    const _Float16* __restrict__ SMh, const _Float16* __restrict__ T1h,
    const _Float16* __restrict__ WhS, const _Float16* __restrict__ WhE,
    const float* __restrict__ scS, const float* __restrict__ scE,
    float* __restrict__ SO, float* __restrict__ RT,
    const int* __restrict__ offs, const int* __restrict__ tlist,
    const float* __restrict__ topp)
{
  int z = blockIdx.z;
  int mbase = 0, mcount = M_;
  const _Float16* Agh = SMh;
  const _Float16* Whb = WhS;
  const float* sc = scS;
  if (z > 0) {
    int e = z - 1;
    mbase = offs[e]; mcount = offs[e + 1] - mbase;
    Agh = T1h;
    Whb = WhE + (size_t)e * 1024 * 2048;
    sc = scE + (size_t)e * 1024;
  }
  int m0 = blockIdx.y * 128;
  if (z > 0 && m0 >= mcount) return;
  int n0 = blockIdx.x * 64;

  __shared__ __align__(16) _Float16 As[4][128][8];
  __shared__ __align__(16) _Float16 Qs[4][64][8];

  int tid = threadIdx.x;
  int lm  = tid >> 1;
  int kcA = (tid & 1) * 16;
  int lw  = tid >> 2;
  int kcW = (tid & 3) * 8;

  int am  = m0 + lm;
  int amc = (z > 0) ? ((am < mcount) ? am : (mcount - 1)) : am;
  int arow = (z > 0) ? (mbase + amc) : am;
  const _Float16* Arh = Agh + (size_t)arow * 2048;
  const _Float16* Wrh = Whb + (size_t)(n0 + lw) * 2048;

  int wv = tid >> 6, lane = tid & 63;
  int wm = wv >> 1, wn = wv & 1;
  int ks = lane >> 4, fr = lane & 15;

  f32x4 acch[4][2];
  #pragma unroll
  for (int i = 0; i < 4; i++)
    #pragma unroll
    for (int j = 0; j < 2; j++) acch[i][j] = (f32x4)0.f;

  for (int kt = 0; kt < 2048; kt += 32) {
    half8 a0 = *reinterpret_cast<const half8*>(Arh + kt + kcA);
    half8 a1 = *reinterpret_cast<const half8*>(Arh + kt + kcA + 8);
    half8 qv = *reinterpret_cast<const half8*>(Wrh + kt + kcW);
    __syncthreads();
    int sA = kcA >> 3;
    *reinterpret_cast<half8*>(&As[sA][lm][0])     = a0;
    *reinterpret_cast<half8*>(&As[sA + 1][lm][0]) = a1;
    *reinterpret_cast<half8*>(&Qs[kcW >> 3][lw][0]) = qv;
    __syncthreads();
    half8 bfr0 = *reinterpret_cast<half8*>(&Qs[ks][wn * 32 + fr][0]);
    half8 bfr1 = *reinterpret_cast<half8*>(&Qs[ks][wn * 32 + 16 + fr][0]);
    #pragma unroll
    for (int i = 0; i < 4; i++) {
      half8 ah = *reinterpret_cast<half8*>(&As[ks][wm * 64 + i * 16 + fr][0]);
      acch[i][0] = __builtin_amdgcn_mfma_f32_16x16x32_f16(ah, bfr0, acch[i][0], 0, 0, 0);
      acch[i][1] = __builtin_amdgcn_mfma_f32_16x16x32_f16(ah, bfr1, acch[i][1], 0, 0, 0);
    }
  }

  #pragma unroll
  for (int j = 0; j < 2; j++) {
    int col = n0 + wn * 32 + j * 16 + fr;
    float scl = sc[col];
    #pragma unroll
    for (int i = 0; i < 4; i++) {
      #pragma unroll
      for (int r = 0; r < 4; r++) {
        int lrow = m0 + wm * 64 + i * 16 + ks * 4 + r;
        if (z > 0 && lrow >= mcount) continue;
        float v = acch[i][j][r] * scl;
        if (z > 0) {
          int orow = tlist[mbase + lrow];
          RT[(size_t)orow * 1024 + col] = v * topp[orow];
        } else {
          SO[(size_t)lrow * 1024 + col] = v;
        }
      }
    }
  }
}

// ===== final add =====
__global__ __launch_bounds__(256) void k_final(const float* __restrict__ x1,
                                               const float* __restrict__ so,
                                               const float* __restrict__ rt,
                                               float* __restrict__ out) {
  #pragma clang fp contract(off)
  int i = blockIdx.x * 256 + threadIdx.x;
  float moe = so[i] + rt[i];
  out[i] = x1[i] + moe;
}

// ===== MFMA flash differential attention (reg-prefetch pipeline + fast exp) =====
__global__ __launch_bounds__(256) void k_attn4(const float* __restrict__ q,
                                               const _Float16* __restrict__ khg,
                                               const _Float16* __restrict__ klg,
                                               const _Float16* __restrict__ vth,
                                               const _Float16* __restrict__ vtl,
                                               const float* __restrict__ lamp,
                                               _Float16* __restrict__ aoh,
                                               _Float16* __restrict__ aol)
{
  __shared__ __align__(16) _Float16 KH[2][64][72];
  __shared__ __align__(16) _Float16 KL[2][64][72];
  __shared__ __align__(16) _Float16 VH[64][72];
  __shared__ __align__(16) _Float16 VL[64][72];
  __shared__ __align__(16) _Float16 PH[4][16][72];
  __shared__ __align__(16) _Float16 PL[4][16][72];

  int bh = blockIdx.x;
  int b = bh >> 4, h = bh & 15;
  int y = blockIdx.y;
  int tq = (y < 8) ? (2 * y) : (31 - 2 * y);
  int t0 = tq * 64;
  int tid = threadIdx.x;
  int wm = tid >> 6, lane = tid & 63;
  int ks = lane >> 4, fr = lane & 15;
  size_t tokbase = (size_t)b * T_;
  float lam = lamp[0];

  half8 qh[2][2], ql[2][2];
  {
    const float* qr = q + (tokbase + t0 + wm * 16 + fr) * 2048 + h * 64;
    #pragma unroll
    for (int g = 0; g < 2; ++g)
      #pragma unroll
      for (int s = 0; s < 2; ++s) {
        const float* p = qr + g * 1024 + s * 32 + ks * 8;
        float4 x0 = *reinterpret_cast<const float4*>(p);
        float4 x1 = *reinterpret_cast<const float4*>(p + 4);
        float xv[8] = {x0.x,x0.y,x0.z,x0.w, x1.x,x1.y,x1.z,x1.w};
        half8 hh, ll;
        #pragma unroll
        for (int j = 0; j < 8; ++j) {
          _Float16 hv = (_Float16)xv[j];
          hh[j] = hv; ll[j] = (_Float16)((xv[j] - (float)hv) * 2048.0f);
        }
        qh[g][s] = hh; ql[g][s] = ll;
      }
  }

  f32x4 Oh[2][4], Ox[2][4];
  #pragma unroll
  for (int g = 0; g < 2; ++g)
    #pragma unroll
    for (int d = 0; d < 4; ++d) { Oh[g][d] = (f32x4)0.f; Ox[g][d] = (f32x4)0.f; }
  float mrun[2][4], lrun[2][4];
  #pragma unroll
  for (int g = 0; g < 2; ++g)
    #pragma unroll
    for (int r = 0; r < 4; ++r) { mrun[g][r] = -1e30f; lrun[g][r] = 0.f; }

  int key = tid & 63;
  int d0 = (tid >> 6) * 16;
  half8 rkh[2][2], rkl[2][2], rvh[2], rvl[2];
  {
    #pragma unroll
    for (int g = 0; g < 2; ++g) {
      const _Float16* sh = khg + (size_t)(tokbase + key) * 2048 + g * 1024 + h * 64 + d0;
      const _Float16* sl = klg + (size_t)(tokbase + key) * 2048 + g * 1024 + h * 64 + d0;
      rkh[g][0] = *reinterpret_cast<const half8*>(sh);
      rkh[g][1] = *reinterpret_cast<const half8*>(sh + 8);
      rkl[g][0] = *reinterpret_cast<const half8*>(sl);
      rkl[g][1] = *reinterpret_cast<const half8*>(sl + 8);
    }
    size_t vb = ((size_t)b * 1024 + h * 64 + key) * 1024 + d0;
    rvh[0] = *reinterpret_cast<const half8*>(vth + vb);
    rvh[1] = *reinterpret_cast<const half8*>(vth + vb + 8);
    rvl[0] = *reinterpret_cast<const half8*>(vtl + vb);
    rvl[1] = *reinterpret_cast<const half8*>(vtl + vb + 8);
  }

  for (int jt = 0; jt <= tq; ++jt) {
    int kv0 = jt * 64;
    __syncthreads();
    #pragma unroll
    for (int g = 0; g < 2; ++g) {
      *reinterpret_cast<half8*>(&KH[g][key][d0])     = rkh[g][0];
      *reinterpret_cast<half8*>(&KH[g][key][d0 + 8]) = rkh[g][1];
      *reinterpret_cast<half8*>(&KL[g][key][d0])     = rkl[g][0];
      *reinterpret_cast<half8*>(&KL[g][key][d0 + 8]) = rkl[g][1];
    }
    *reinterpret_cast<half8*>(&VH[key][d0])     = rvh[0];
    *reinterpret_cast<half8*>(&VH[key][d0 + 8]) = rvh[1];
    *reinterpret_cast<half8*>(&VL[key][d0])     = rvl[0];
    *reinterpret_cast<half8*>(&VL[key][d0 + 8]) = rvl[1];
    if (jt < tq) {
      int nv0 = kv0 + 64;
      #pragma unroll
      for (int g = 0; g < 2; ++g) {
        const _Float16* sh = khg + (size_t)(tokbase + nv0 + key) * 2048 + g * 1024 + h * 64 + d0;
        const _Float16* sl = klg + (size_t)(tokbase + nv0 + key) * 2048 + g * 1024 + h * 64 + d0;
        rkh[g][0] = *reinterpret_cast<const half8*>(sh);
        rkh[g][1] = *reinterpret_cast<const half8*>(sh + 8);
        rkl[g][0] = *reinterpret_cast<const half8*>(sl);
        rkl[g][1] = *reinterpret_cast<const half8*>(sl + 8);
      }
      size_t vb = ((size_t)b * 1024 + h * 64 + key) * 1024 + nv0 + d0;
      rvh[0] = *reinterpret_cast<const half8*>(vth + vb);
      rvh[1] = *reinterpret_cast<const half8*>(vth + vb + 8);
      rvl[0] = *reinterpret_cast<const half8*>(vtl + vb);
      rvl[1] = *reinterpret_cast<const half8*>(vtl + vb + 8);
    }
    __syncthreads();

    bool diag = (jt == tq);
    #pragma unroll
    for (int g = 0; g < 2; ++g) {
      f32x4 Sh[4], Sx[4];
      #pragma unroll
      for (int kf = 0; kf < 4; ++kf) { Sh[kf] = (f32x4)0.f; Sx[kf] = (f32x4)0.f; }
      #pragma unroll
      for (int s = 0; s < 2; ++s) {
        #pragma unroll
        for (int kf = 0; kf < 4; ++kf) {
          half8 kh = *reinterpret_cast<half8*>(&KH[g][kf * 16 + fr][s * 32 + ks * 8]);
          half8 kl = *reinterpret_cast<half8*>(&KL[g][kf * 16 + fr][s * 32 + ks * 8]);
          Sh[kf] = __builtin_amdgcn_mfma_f32_16x16x32_f16(qh[g][s], kh, Sh[kf], 0, 0, 0);
          Sx[kf] = __builtin_amdgcn_mfma_f32_16x16x32_f16(qh[g][s], kl, Sx[kf], 0, 0, 0);
          Sx[kf] = __builtin_amdgcn_mfma_f32_16x16x32_f16(ql[g][s], kh, Sx[kf], 0, 0, 0);
        }
      }
      float sv[4][4];
      #pragma unroll
      for (int kf = 0; kf < 4; ++kf)
        #pragma unroll
        for (int r = 0; r < 4; ++r) {
          float s_ = (Sh[kf][r] + Sx[kf][r] * (1.0f / 2048.0f)) * 0.125f;
          if (diag) {
            int row_abs = t0 + wm * 16 + ks * 4 + r;
            int col_abs = kv0 + kf * 16 + fr;
            if (col_abs > row_abs) s_ = -1e30f;
          }
          sv[kf][r] = s_;
        }
      #pragma unroll
      for (int r = 0; r < 4; ++r) {
        float tmax = fmaxf(fmaxf(sv[0][r], sv[1][r]), fmaxf(sv[2][r], sv[3][r]));
        #pragma unroll
        for (int msk = 1; msk < 16; msk <<= 1) tmax = fmaxf(tmax, __shfl_xor(tmax, msk));
        bool up = tmax > mrun[g][r];
        float mnew = up ? tmax : mrun[g][r];
        float e0 = __expf(sv[0][r] - mnew);
        float e1 = __expf(sv[1][r] - mnew);
        float e2 = __expf(sv[2][r] - mnew);
        float e3 = __expf(sv[3][r] - mnew);
        float rsum = (e0 + e1) + (e2 + e3);
        #pragma unroll
        for (int msk = 1; msk < 16; msk <<= 1) rsum += __shfl_xor(rsum, msk);
        if (up) {
          float scale = __expf(mrun[g][r] - tmax);
          lrun[g][r] = lrun[g][r] * scale + rsum;
          mrun[g][r] = tmax;
          #pragma unroll
          for (int df = 0; df < 4; ++df) { Oh[g][df][r] *= scale; Ox[g][df][r] *= scale; }
        } else {
          lrun[g][r] += rsum;
        }
        float ev[4] = {e0, e1, e2, e3};
        #pragma unroll
        for (int kf = 0; kf < 4; ++kf) {
          _Float16 ph = (_Float16)ev[kf];
          _Float16 pl = (_Float16)((ev[kf] - (float)ph) * 2048.0f);
          PH[wm][ks * 4 + r][kf * 16 + fr] = ph;
          PL[wm][ks * 4 + r][kf * 16 + fr] = pl;
        }
      }
      #pragma unroll
      for (int s = 0; s < 2; ++s) {
        half8 pah = *reinterpret_cast<half8*>(&PH[wm][fr][s * 32 + ks * 8]);
        half8 pal = *reinterpret_cast<half8*>(&PL[wm][fr][s * 32 + ks * 8]);
        #pragma unroll
        for (int df = 0; df < 4; ++df) {
          half8 vh = *reinterpret_cast<half8*>(&VH[df * 16 + fr][s * 32 + ks * 8]);
          half8 vl = *reinterpret_cast<half8*>(&VL[df * 16 + fr][s * 32 + ks * 8]);
          Oh[g][df] = __builtin_amdgcn_mfma_f32_16x16x32_f16(pah, vh, Oh[g][df], 0, 0, 0);
          Ox[g][df] = __builtin_amdgcn_mfma_f32_16x16x32_f16(pah, vl, Ox[g][df], 0, 0, 0);
          Ox[g][df] = __builtin_amdgcn_mfma_f32_16x16x32_f16(pal, vh, Ox[g][df], 0, 0, 0);
        }
      }
    }
  }

  #pragma unroll
  for (int df = 0; df < 4; ++df) {
    #pragma unroll
    for (int r = 0; r < 4; ++r) {
      int row_abs = t0 + wm * 16 + ks * 4 + r;
      int d = df * 16 + fr;
      float o1 = (Oh[0][df][r] + Ox[0][df][r] * (1.0f / 2048.0f)) / lrun[0][r];
      float o2 = (Oh[1][df][r] + Ox[1][df][r] * (1.0f / 2048.0f)) / lrun[1][r];
      float oo = o1 - lam * o2;
      size_t idx = (tokbase + row_abs) * 1024 + h * 64 + d;
      _Float16 hv = (_Float16)oo;
      aoh[idx] = hv;
      aol[idx] = (_Float16)((oo - (float)hv) * 2048.0f);
    }
  }
}

// ===== router =====
__global__ __launch_bounds__(256) void k_router(const float* __restrict__ hm,
                                                const float* __restrict__ rw,
                                                int* __restrict__ idx,
                                                float* __restrict__ topp)
{
  #pragma clang fp contract(off)
  int tid = threadIdx.x;
  int tg = tid >> 3, e = tid & 7;
  int m = blockIdx.x * 32 + tg;
  const float* hr = hm + (size_t)m * 1024;
  const float* wr = rw + (size_t)e * 1024;
  float l = 0.f;
  for (int dd = 0; dd < 1024; ++dd) l = __builtin_fmaf(hr[dd], wr[dd], l);
  float mx = l;
  #pragma unroll
  for (int off = 1; off < 8; off <<= 1) mx = fmaxf(mx, __shfl_xor(mx, off, 8));
  float p = __expf(l - mx);
  float den = p;
  #pragma unroll
  for (int off = 1; off < 8; off <<= 1) den += __shfl_xor(den, off, 8);
  float prob = p / den;
  float pm = prob;
  #pragma unroll
  for (int off = 1; off < 8; off <<= 1) pm = fmaxf(pm, __shfl_xor(pm, off, 8));
  unsigned long long ball = __ballot(prob == pm);
  int grp = (tid & 63) >> 3;
  int first = __ffsll((unsigned long long)((ball >> (grp * 8)) & 0xFFull)) - 1;
  if (e == 0) { idx[m] = first; topp[m] = pm; }
}

// ===== deterministic token compaction =====
__global__ __launch_bounds__(512) void k_route_fill(const int* __restrict__ idx,
                                                    int* __restrict__ offs,
                                                    int* __restrict__ tlist)
{
  __shared__ int cnt[8];
  __shared__ int off[9];
  int w = threadIdx.x >> 6, lane = threadIdx.x & 63;
  int total = 0;
  for (int it = 0; it < M_ / 64; ++it) {
    int tok = it * 64 + lane;
    unsigned long long m = __ballot(idx[tok] == w);
    total += __popcll(m);
  }
  if (lane == 0) cnt[w] = total;
  __syncthreads();
  if (threadIdx.x == 0) {
    int o = 0;
    for (int e = 0; e < 8; ++e) { off[e] = o; o += cnt[e]; }
    off[8] = o;
    for (int e = 0; e < 9; ++e) offs[e] = off[e];
  }
  __syncthreads();
  int base = off[w];
  for (int it = 0; it < M_ / 64; ++it) {
    int tok = it * 64 + lane;
    bool sel = (idx[tok] == w);
    unsigned long long m = __ballot(sel);
    if (sel) {
      int pos = base + __popcll(m & ((1ull << lane) - 1ull));
      tlist[pos] = tok;
    }
    base += __popcll(m);
  }
}

extern "C" void kernel_launch(void* const* d_in, const int* in_sizes, int n_in,
                              void* d_out, int out_size, void* d_ws, size_t ws_size,
                              hipStream_t stream) {
  const float* x   = (const float*)d_in[0];
  const float* Wq  = (const float*)d_in[2];
  const float* Wk  = (const float*)d_in[3];
  const float* Wv  = (const float*)d_in[4];
  const float* Wo  = (const float*)d_in[5];
  const float* lq  = (const float*)d_in[6];
  const float* lk  = (const float*)d_in[7];
  const float* qng = (const float*)d_in[8];
  const float* qnb = (const float*)d_in[9];
  const float* kng = (const float*)d_in[10];
  const float* knb = (const float*)d_in[11];
  const float* ag  = (const float*)d_in[12];
  const float* ab  = (const float*)d_in[13];
  const float* fg  = (const float*)d_in[14];
  const float* fb  = (const float*)d_in[15];
  const float* mg  = (const float*)d_in[16];
  const float* mb  = (const float*)d_in[17];
  const float* sw1 = (const float*)d_in[18];
  const float* sw2 = (const float*)d_in[19];
  const float* ew1 = (const float*)d_in[20];
  const float* ew2 = (const float*)d_in[21];
  const float* rw  = (const float*)d_in[22];

  float* ws = (float*)d_ws;
  size_t o = 0;
  float* scWq = ws + o; o += 2048;
  float* scWk = ws + o; o += 2048;
  float* scWv = ws + o; o += 1024;
  float* scWo = ws + o; o += 1024;
  float* scS1 = ws + o; o += 2048;
  float* scS2 = ws + o; o += 1024;
  float* scE1 = ws + o; o += 8 * 2048;
  float* scE2 = ws + o; o += 8 * 1024;
  float* lam  = ws + o; o += 16;
  float* TOPP = ws + o; o += 2048;
  int*   IDX  = (int*)(ws + o); o += 2048;
  int*   OFFS = (int*)(ws + o); o += 16;
  int*   TLIST= (int*)(ws + o); o += 2048;
  o = (o + 15) & ~(size_t)15;

  _Float16* QWq = (_Float16*)(ws + o); o += 1024 * 1024;
  _Float16* QWk = (_Float16*)(ws + o); o += 1024 * 1024;
  _Float16* QWv = (_Float16*)(ws + o); o += 512 * 1024;
  _Float16* QWo = (_Float16*)(ws + o); o += 512 * 1024;
  _Float16* QS1 = (_Float16*)(ws + o); o += 1024 * 1024;
  _Float16* QS2 = (_Float16*)(ws + o); o += 1024 * 1024;
  _Float16* QE1 = (_Float16*)(ws + o); o += 8 * 1024 * 1024;
  _Float16* QE2 = (_Float16*)(ws + o); o += 8 * 1024 * 1024;

  float* RA = ws + o; o += 2 * 1024 * 1024;
  _Float16* H1h = (_Float16*)RA;
  _Float16* H1l = (_Float16*)(RA + 1024 * 1024);
  _Float16* SMh = (_Float16*)RA;
  float* RB = ws + o; o += 2 * 1024 * 1024;
  _Float16* AOh = (_Float16*)RB;
  _Float16* AOl = (_Float16*)(RB + 1024 * 1024);
  _Float16* HMh = (_Float16*)RB;
  _Float16* T1h = (_Float16*)(ws + o); o += 2 * 1024 * 1024;

  const size_t MQ = (size_t)M_ * 2048;
  float* QP = ws + o; o += MQ;
  float* KP = ws + o; o += MQ;
  _Float16* KHg = (_Float16*)(ws + o); o += 2 * 1024 * 1024;
  _Float16* KLg = (_Float16*)(ws + o); o += 2 * 1024 * 1024;
  _Float16* VTH = (_Float16*)(ws + o); o += 1024 * 1024;
  _Float16* VTL = (_Float16*)(ws + o); o += 1024 * 1024;

  float* X1 = QP;
  float* HM = QP + MQ / 2;
  float* SO = KP;
  float* RT = (float*)KHg;

  // scales + prequant + lambda (one launch)
  k_scaleq_all<<<33793, 64, 0, stream>>>(Wq, Wk, Wv, Wo, sw1, sw2, ew1, ew2, lq, lk,
                                         scWq, scWk, scWv, scWo, scS1, scS2, scE1, scE2,
                                         QWq, QWk, QWv, QWo, QS1, QS2, QE1, QE2, lam);

  // attention block (router path: DUAL)
  k_layernorm_split<<<M_, 256, 0, stream>>>(x, ag, ab, H1h, H1l, 1024);
  k_mgemm_qkv<<<dim3(80,16), 256, 0, stream>>>(H1h, H1l, QWq, QWk, QWv, scWq, scWk, scWv, QP, KP, VTH, VTL);
  k_lnqk<<<2 * M_, 256, 0, stream>>>(QP, qng, qnb, KP, kng, knb, KHg, KLg);
  k_attn4<<<dim3(32, 16), 256, 0, stream>>>(QP, KHg, KLg, VTH, VTL, lam, AOh, AOl);
  k_mgemm<2,0,1><<<dim3(16,16), 256, 0, stream>>>(AOh, AOl, 1024, QWo, scWo, X1, nullptr, nullptr, 1024, 1024, 1024, x, nullptr, nullptr, nullptr, nullptr);

  // MoE block
  k_lnln<<<M_, 256, 0, stream>>>(X1, fg, fb, mg, mb, HM, HMh);
  k_router<<<M_ / 32, 256, 0, stream>>>(HM, rw, IDX, TOPP);
  k_route_fill<<<1, 512, 0, stream>>>(IDX, OFFS, TLIST);

  // fused MoE GEMMs (NLOOP=1 — occupancy wins over A-reuse here)
  k_mgemm_moe1<<<dim3(32,16,9), 256, 0, stream>>>(HMh, QS1, QE1, scS1, scE1, SMh, T1h, OFFS, TLIST);
  k_mgemm_moe2<<<dim3(16,16,9), 256, 0, stream>>>(SMh, T1h, QS2, QE2, scS2, scE2, SO, RT, OFFS, TLIST, TOPP);

  k_final<<<8192, 256, 0, stream>>>(X1, SO, RT, (float*)d_out);
}